// Round 1
// baseline (1747.942 us; speedup 1.0000x reference)
//
#include <hip/hip_runtime.h>
#include <math.h>

#define BLOCK 256
#define GRID  2048

// Pass 1: histogram of bin indices. Integer atomics -> deterministic.
__global__ __launch_bounds__(BLOCK) void ghm_hist_kernel(
    const float4* __restrict__ x, const float4* __restrict__ t,
    int* __restrict__ hist, int n4, float scale, int nbin_m1) {
  int i = blockIdx.x * blockDim.x + threadIdx.x;
  int stride = gridDim.x * blockDim.x;
  for (; i < n4; i += stride) {
    float4 xv = x[i];
    float4 tv = t[i];
    float gx[4] = {fabsf(xv.x - tv.x), fabsf(xv.y - tv.y),
                   fabsf(xv.z - tv.z), fabsf(xv.w - tv.w)};
#pragma unroll
    for (int k = 0; k < 4; ++k) {
      int b = (int)(gx[k] * scale);  // g >= 0, trunc == floor
      if (b > nbin_m1) b = nbin_m1;
      atomicAdd(&hist[b], 1);
    }
  }
}

// Pass 2: count non-empty bins. Wave shuffle reduce, one int atomic per wave.
__global__ __launch_bounds__(BLOCK) void ghm_nz_kernel(
    const int* __restrict__ hist, int nbin, int* __restrict__ nz) {
  int i = blockIdx.x * blockDim.x + threadIdx.x;
  int stride = gridDim.x * blockDim.x;
  int c = 0;
  for (; i < nbin; i += stride) c += (hist[i] > 0) ? 1 : 0;
#pragma unroll
  for (int off = 32; off > 0; off >>= 1) c += __shfl_down(c, off, 64);
  if ((threadIdx.x & 63) == 0) atomicAdd(nz, c);
}

// Pass 3: weighted BCE, per-thread double accumulate, deterministic block tree
// reduce -> per-block partial sums.
__global__ __launch_bounds__(BLOCK) void ghm_loss_kernel(
    const float4* __restrict__ x, const float4* __restrict__ t,
    const int* __restrict__ hist, const int* __restrict__ nz,
    double* __restrict__ partials, int n4, float scale, int nbin_m1, float fN) {
  float nzf = (float)(*nz);
  double acc = 0.0;
  int i = blockIdx.x * blockDim.x + threadIdx.x;
  int stride = gridDim.x * blockDim.x;
  for (; i < n4; i += stride) {
    float4 xv = x[i];
    float4 tv = t[i];
    float xs[4] = {xv.x, xv.y, xv.z, xv.w};
    float ts[4] = {tv.x, tv.y, tv.z, tv.w};
    float s = 0.0f;
#pragma unroll
    for (int k = 0; k < 4; ++k) {
      float g = fabsf(xs[k] - ts[k]);
      int b = (int)(g * scale);
      if (b > nbin_m1) b = nbin_m1;
      float cnt = (float)hist[b];
      float gd = fmaxf(cnt * nzf, 1.0f);
      float w = fN / gd;
      float bce = -(ts[k] * logf(xs[k]) + (1.0f - ts[k]) * logf(1.0f - xs[k]));
      s += bce * w;
    }
    acc += (double)s;
  }
  __shared__ double sm[BLOCK];
  sm[threadIdx.x] = acc;
  __syncthreads();
  for (int off = BLOCK / 2; off > 0; off >>= 1) {
    if (threadIdx.x < off) sm[threadIdx.x] += sm[threadIdx.x + off];
    __syncthreads();
  }
  if (threadIdx.x == 0) partials[blockIdx.x] = sm[0];
}

// Pass 4: fixed-order final reduce of GRID partials -> mean -> d_out[0].
__global__ __launch_bounds__(BLOCK) void ghm_final_kernel(
    const double* __restrict__ partials, float* __restrict__ out, int nparts,
    double invN) {
  __shared__ double sm[BLOCK];
  double a = 0.0;
  for (int i = threadIdx.x; i < nparts; i += BLOCK) a += partials[i];
  sm[threadIdx.x] = a;
  __syncthreads();
  for (int off = BLOCK / 2; off > 0; off >>= 1) {
    if (threadIdx.x < off) sm[threadIdx.x] += sm[threadIdx.x + off];
    __syncthreads();
  }
  if (threadIdx.x == 0) out[0] = (float)(sm[0] * invN);
}

extern "C" void kernel_launch(void* const* d_in, const int* in_sizes, int n_in,
                              void* d_out, int out_size, void* d_ws,
                              size_t ws_size, hipStream_t stream) {
  const float* x = (const float*)d_in[0];
  const float* t = (const float*)d_in[1];
  float* out = (float*)d_out;

  long long N = (long long)in_sizes[0];  // 4096*8192 = 33554432
  int nbin = (int)(N / 10);              // 3355443
  // Reproduce jnp's f32 weak-type promotion: scale rounds to (float)nbin.
  float scale = (float)((double)nbin - 0.0001);
  int n4 = (int)(N / 4);

  // Workspace layout: [hist: nbin int][nz: 1 int][pad to 8][partials: GRID dbl]
  int* hist = (int*)d_ws;
  size_t hist_bytes = (size_t)nbin * 4;
  int* nz = (int*)((char*)d_ws + hist_bytes);
  size_t part_off = (hist_bytes + 4 + 7) & ~(size_t)7;
  double* partials = (double*)((char*)d_ws + part_off);

  // Zero hist + nz every call (ws is poisoned once, never re-poisoned).
  hipMemsetAsync(d_ws, 0, part_off, stream);

  ghm_hist_kernel<<<GRID, BLOCK, 0, stream>>>(
      (const float4*)x, (const float4*)t, hist, n4, scale, nbin - 1);
  ghm_nz_kernel<<<GRID, BLOCK, 0, stream>>>(hist, nbin, nz);
  ghm_loss_kernel<<<GRID, BLOCK, 0, stream>>>(
      (const float4*)x, (const float4*)t, hist, nz, partials, n4, scale,
      nbin - 1, (float)N);
  ghm_final_kernel<<<1, BLOCK, 0, stream>>>(partials, out, GRID,
                                            1.0 / (double)N);
}

// Round 2
// 790.793 us; speedup vs baseline: 2.2104x; 2.2104x over previous
//
#include <hip/hip_runtime.h>
#include <math.h>

// ---------------- fast path geometry ----------------
#define SC_BLOCKS 512          // stripe blocks for K1/K3 (per-block hists)
#define SC_THREADS 256
#define BPB 4096               // bins per bucket (power of two)
#define BPB_SHIFT 12
#define NB_PAD 1024            // padded bucket-array stride (>= nb)

__device__ __forceinline__ int bin_of(float xv, float tv, float scale,
                                      int nbin_m1) {
  float g = fabsf(xv - tv);
  int b = (int)(g * scale);  // g >= 0 -> trunc == floor
  return b > nbin_m1 ? nbin_m1 : b;
}

// K1: per-block coarse bucket histogram (LDS), write one row per block.
__global__ __launch_bounds__(SC_THREADS) void k1_count(
    const float4* __restrict__ x, const float4* __restrict__ t,
    unsigned* __restrict__ hists /*[SC_BLOCKS][NB_PAD]*/, int per_block_f4,
    float scale, int nbin_m1) {
  __shared__ unsigned cnt[NB_PAD];
  for (int i = threadIdx.x; i < NB_PAD; i += SC_THREADS) cnt[i] = 0;
  __syncthreads();
  int base = blockIdx.x * per_block_f4;
  for (int i = threadIdx.x; i < per_block_f4; i += SC_THREADS) {
    float4 xv = x[base + i];
    float4 tv = t[base + i];
    atomicAdd(&cnt[bin_of(xv.x, tv.x, scale, nbin_m1) >> BPB_SHIFT], 1u);
    atomicAdd(&cnt[bin_of(xv.y, tv.y, scale, nbin_m1) >> BPB_SHIFT], 1u);
    atomicAdd(&cnt[bin_of(xv.z, tv.z, scale, nbin_m1) >> BPB_SHIFT], 1u);
    atomicAdd(&cnt[bin_of(xv.w, tv.w, scale, nbin_m1) >> BPB_SHIFT], 1u);
  }
  __syncthreads();
  unsigned* row = hists + (size_t)blockIdx.x * NB_PAD;
  for (int i = threadIdx.x; i < NB_PAD; i += SC_THREADS) row[i] = cnt[i];
}

// K2a: per-bucket exclusive scan over the SC_BLOCKS block-rows.
// grid = nb blocks, block = SC_BLOCKS threads.
__global__ __launch_bounds__(SC_BLOCKS) void k2a_colscan(
    const unsigned* __restrict__ hists, unsigned* __restrict__ rel,
    unsigned* __restrict__ colsum) {
  __shared__ unsigned v[SC_BLOCKS];
  int b = blockIdx.x;
  int g = threadIdx.x;
  unsigned val = hists[(size_t)g * NB_PAD + b];
  v[g] = val;
  __syncthreads();
  for (int off = 1; off < SC_BLOCKS; off <<= 1) {
    unsigned a = (g >= off) ? v[g - off] : 0u;
    __syncthreads();
    v[g] += a;
    __syncthreads();
  }
  rel[(size_t)g * NB_PAD + b] = v[g] - val;  // exclusive prefix
  if (g == SC_BLOCKS - 1) colsum[b] = v[g];  // bucket total
}

// K2b: exclusive scan of bucket totals -> bucket starts. 1 block, 1024 thr.
__global__ __launch_bounds__(1024) void k2b_scan(
    const unsigned* __restrict__ colsum, unsigned* __restrict__ start,
    int nb) {
  __shared__ unsigned v[1024];
  int i = threadIdx.x;
  unsigned val = (i < nb) ? colsum[i] : 0u;
  v[i] = val;
  __syncthreads();
  for (int off = 1; off < 1024; off <<= 1) {
    unsigned a = (i >= off) ? v[i - off] : 0u;
    __syncthreads();
    v[i] += a;
    __syncthreads();
  }
  if (i < nb) start[i] = v[i] - val;
}

// K3: scatter packed (bin_low<<20 | bce_q20) keys to exact per-(block,bucket)
// regions. No global atomics; ranks via LDS cursors.
__global__ __launch_bounds__(SC_THREADS) void k3_scatter(
    const float4* __restrict__ x, const float4* __restrict__ t,
    const unsigned* __restrict__ rel, const unsigned* __restrict__ start,
    unsigned* __restrict__ keys, int per_block_f4, float scale, int nbin_m1,
    int nb) {
  __shared__ unsigned cur[NB_PAD];
  const unsigned* relrow = rel + (size_t)blockIdx.x * NB_PAD;
  for (int i = threadIdx.x; i < nb; i += SC_THREADS)
    cur[i] = start[i] + relrow[i];
  __syncthreads();
  int base = blockIdx.x * per_block_f4;
  for (int i = threadIdx.x; i < per_block_f4; i += SC_THREADS) {
    float4 xv = x[base + i];
    float4 tv = t[base + i];
    float xs[4] = {xv.x, xv.y, xv.z, xv.w};
    float ts[4] = {tv.x, tv.y, tv.z, tv.w};
#pragma unroll
    for (int k = 0; k < 4; ++k) {
      int b = bin_of(xs[k], ts[k], scale, nbin_m1);
      float bce =
          -(ts[k] * logf(xs[k]) + (1.0f - ts[k]) * logf(1.0f - xs[k]));
      unsigned q = (unsigned)(bce * 65536.0f + 0.5f);
      if (q > 0xFFFFFu) q = 0xFFFFFu;
      unsigned key = ((unsigned)(b & (BPB - 1)) << 20) | q;
      unsigned r = atomicAdd(&cur[b >> BPB_SHIFT], 1u);
      keys[r] = key;
    }
  }
}

// K4: one block per bucket. LDS per-bin count + f32 bce-sum, then
// S_b = sum(bin_sum/bin_cnt), nz_b = #nonzero bins. f64 block reduce.
__global__ __launch_bounds__(256) void k4_bucket(
    const unsigned* __restrict__ keys, const unsigned* __restrict__ start,
    const unsigned* __restrict__ colsum, double* __restrict__ S_part,
    unsigned* __restrict__ nz) {
  __shared__ unsigned cnt[BPB];
  __shared__ float sum[BPB];
  __shared__ double red[256];
  __shared__ unsigned redi[256];
  int b = blockIdx.x;
  for (int i = threadIdx.x; i < BPB; i += 256) {
    cnt[i] = 0;
    sum[i] = 0.0f;
  }
  __syncthreads();
  unsigned s0 = start[b], c = colsum[b];
  for (unsigned i = threadIdx.x; i < c; i += 256) {
    unsigned k = keys[s0 + i];
    unsigned lo = k >> 20;
    float bce = (float)(k & 0xFFFFFu) * (1.0f / 65536.0f);
    atomicAdd(&cnt[lo], 1u);
    atomicAdd(&sum[lo], bce);
  }
  __syncthreads();
  double S = 0.0;
  unsigned z = 0;
  for (int i = threadIdx.x; i < BPB; i += 256) {
    unsigned cc = cnt[i];
    if (cc) {
      z++;
      S += (double)(sum[i] / (float)cc);
    }
  }
  red[threadIdx.x] = S;
  redi[threadIdx.x] = z;
  __syncthreads();
  for (int off = 128; off > 0; off >>= 1) {
    if (threadIdx.x < off) {
      red[threadIdx.x] += red[threadIdx.x + off];
      redi[threadIdx.x] += redi[threadIdx.x + off];
    }
    __syncthreads();
  }
  if (threadIdx.x == 0) {
    S_part[b] = red[0];
    atomicAdd(nz, redi[0]);
  }
}

// K5: final scalar: out = (sum_b S_b) / nz.
__global__ __launch_bounds__(256) void k5_final(
    const double* __restrict__ S_part, const unsigned* __restrict__ nz,
    float* __restrict__ out, int nb) {
  __shared__ double red[256];
  double s = 0.0;
  for (int i = threadIdx.x; i < nb; i += 256) s += S_part[i];
  red[threadIdx.x] = s;
  __syncthreads();
  for (int off = 128; off > 0; off >>= 1) {
    if (threadIdx.x < off) red[threadIdx.x] += red[threadIdx.x + off];
    __syncthreads();
  }
  if (threadIdx.x == 0) out[0] = (float)(red[0] / (double)(*nz));
}

// ---------------- fallback path (proven round-1 kernels) ----------------
#define FB_BLOCK 256
#define FB_GRID 2048

__global__ __launch_bounds__(FB_BLOCK) void ghm_hist_kernel(
    const float4* __restrict__ x, const float4* __restrict__ t,
    int* __restrict__ hist, int n4, float scale, int nbin_m1) {
  int i = blockIdx.x * blockDim.x + threadIdx.x;
  int stride = gridDim.x * blockDim.x;
  for (; i < n4; i += stride) {
    float4 xv = x[i];
    float4 tv = t[i];
    float gx[4] = {fabsf(xv.x - tv.x), fabsf(xv.y - tv.y),
                   fabsf(xv.z - tv.z), fabsf(xv.w - tv.w)};
#pragma unroll
    for (int k = 0; k < 4; ++k) {
      int b = (int)(gx[k] * scale);
      if (b > nbin_m1) b = nbin_m1;
      atomicAdd(&hist[b], 1);
    }
  }
}

__global__ __launch_bounds__(FB_BLOCK) void ghm_nz_kernel(
    const int* __restrict__ hist, int nbin, int* __restrict__ nz) {
  int i = blockIdx.x * blockDim.x + threadIdx.x;
  int stride = gridDim.x * blockDim.x;
  int c = 0;
  for (; i < nbin; i += stride) c += (hist[i] > 0) ? 1 : 0;
#pragma unroll
  for (int off = 32; off > 0; off >>= 1) c += __shfl_down(c, off, 64);
  if ((threadIdx.x & 63) == 0) atomicAdd(nz, c);
}

__global__ __launch_bounds__(FB_BLOCK) void ghm_loss_kernel(
    const float4* __restrict__ x, const float4* __restrict__ t,
    const int* __restrict__ hist, const int* __restrict__ nz,
    double* __restrict__ partials, int n4, float scale, int nbin_m1,
    float fN) {
  float nzf = (float)(*nz);
  double acc = 0.0;
  int i = blockIdx.x * blockDim.x + threadIdx.x;
  int stride = gridDim.x * blockDim.x;
  for (; i < n4; i += stride) {
    float4 xv = x[i];
    float4 tv = t[i];
    float xs[4] = {xv.x, xv.y, xv.z, xv.w};
    float ts[4] = {tv.x, tv.y, tv.z, tv.w};
    float s = 0.0f;
#pragma unroll
    for (int k = 0; k < 4; ++k) {
      float g = fabsf(xs[k] - ts[k]);
      int b = (int)(g * scale);
      if (b > nbin_m1) b = nbin_m1;
      float cntv = (float)hist[b];
      float gd = fmaxf(cntv * nzf, 1.0f);
      float w = fN / gd;
      float bce = -(ts[k] * logf(xs[k]) + (1.0f - ts[k]) * logf(1.0f - xs[k]));
      s += bce * w;
    }
    acc += (double)s;
  }
  __shared__ double sm[FB_BLOCK];
  sm[threadIdx.x] = acc;
  __syncthreads();
  for (int off = FB_BLOCK / 2; off > 0; off >>= 1) {
    if (threadIdx.x < off) sm[threadIdx.x] += sm[threadIdx.x + off];
    __syncthreads();
  }
  if (threadIdx.x == 0) partials[blockIdx.x] = sm[0];
}

__global__ __launch_bounds__(FB_BLOCK) void ghm_final_kernel(
    const double* __restrict__ partials, float* __restrict__ out, int nparts,
    double invN) {
  __shared__ double sm[FB_BLOCK];
  double a = 0.0;
  for (int i = threadIdx.x; i < nparts; i += FB_BLOCK) a += partials[i];
  sm[threadIdx.x] = a;
  __syncthreads();
  for (int off = FB_BLOCK / 2; off > 0; off >>= 1) {
    if (threadIdx.x < off) sm[threadIdx.x] += sm[threadIdx.x + off];
    __syncthreads();
  }
  if (threadIdx.x == 0) out[0] = (float)(sm[0] * invN);
}

extern "C" void kernel_launch(void* const* d_in, const int* in_sizes, int n_in,
                              void* d_out, int out_size, void* d_ws,
                              size_t ws_size, hipStream_t stream) {
  const float* x = (const float*)d_in[0];
  const float* t = (const float*)d_in[1];
  float* out = (float*)d_out;

  long long N = (long long)in_sizes[0];  // 33554432
  int nbin = (int)(N / 10);              // 3355443
  float scale = (float)((double)nbin - 0.0001);  // == f32(nbin) here
  int n4 = (int)(N / 4);
  int nb = (nbin + BPB - 1) / BPB;  // 820 buckets

  // fast-path workspace layout
  size_t off_hists = 0;
  size_t off_rel = off_hists + (size_t)SC_BLOCKS * NB_PAD * 4;
  size_t off_start = off_rel + (size_t)SC_BLOCKS * NB_PAD * 4;
  size_t off_colsum = off_start + NB_PAD * 4;
  size_t off_nz = off_colsum + NB_PAD * 4;
  size_t off_Spart = off_nz + 4096;
  size_t off_keys = off_Spart + NB_PAD * 8;
  size_t needed = off_keys + (size_t)N * 4;

  bool fast = (ws_size >= needed) && (n4 % SC_BLOCKS == 0) && (nb <= NB_PAD) &&
              (N % 4 == 0);

  if (fast) {
    unsigned* hists = (unsigned*)((char*)d_ws + off_hists);
    unsigned* rel = (unsigned*)((char*)d_ws + off_rel);
    unsigned* start = (unsigned*)((char*)d_ws + off_start);
    unsigned* colsum = (unsigned*)((char*)d_ws + off_colsum);
    unsigned* nz = (unsigned*)((char*)d_ws + off_nz);
    double* S_part = (double*)((char*)d_ws + off_Spart);
    unsigned* keys = (unsigned*)((char*)d_ws + off_keys);
    int per_block_f4 = n4 / SC_BLOCKS;

    hipMemsetAsync(nz, 0, 4, stream);
    k1_count<<<SC_BLOCKS, SC_THREADS, 0, stream>>>(
        (const float4*)x, (const float4*)t, hists, per_block_f4, scale,
        nbin - 1);
    k2a_colscan<<<nb, SC_BLOCKS, 0, stream>>>(hists, rel, colsum);
    k2b_scan<<<1, 1024, 0, stream>>>(colsum, start, nb);
    k3_scatter<<<SC_BLOCKS, SC_THREADS, 0, stream>>>(
        (const float4*)x, (const float4*)t, rel, start, keys, per_block_f4,
        scale, nbin - 1, nb);
    k4_bucket<<<nb, 256, 0, stream>>>(keys, start, colsum, S_part, nz);
    k5_final<<<1, 256, 0, stream>>>(S_part, nz, out, nb);
  } else {
    // round-1 proven path
    int* hist = (int*)d_ws;
    size_t hist_bytes = (size_t)nbin * 4;
    int* nzi = (int*)((char*)d_ws + hist_bytes);
    size_t part_off = (hist_bytes + 4 + 7) & ~(size_t)7;
    double* partials = (double*)((char*)d_ws + part_off);

    hipMemsetAsync(d_ws, 0, part_off, stream);
    ghm_hist_kernel<<<FB_GRID, FB_BLOCK, 0, stream>>>(
        (const float4*)x, (const float4*)t, hist, n4, scale, nbin - 1);
    ghm_nz_kernel<<<FB_GRID, FB_BLOCK, 0, stream>>>(hist, nbin, (int*)nzi);
    ghm_loss_kernel<<<FB_GRID, FB_BLOCK, 0, stream>>>(
        (const float4*)x, (const float4*)t, hist, (const int*)nzi, partials,
        n4, scale, nbin - 1, (float)N);
    ghm_final_kernel<<<1, FB_BLOCK, 0, stream>>>(partials, out, FB_GRID,
                                                 1.0 / (double)N);
  }
}

// Round 3
// 443.296 us; speedup vs baseline: 3.9431x; 1.7839x over previous
//
#include <hip/hip_runtime.h>
#include <math.h>

// ---------------- fast path geometry ----------------
#define SC_BLOCKS 512   // stripe blocks for K1/K3 (per-block bucket hists)
#define SC_THREADS 512
#define BPB 16384       // bins per bucket (power of two)
#define BPB_SHIFT 14
#define NB_PAD 256      // padded bucket-array stride (>= nb = 205)
#define QBITS 18
#define QMASK ((1u << QBITS) - 1u)
#define QSCALE 16384.0f  // 2^14: q = bce * 2^14, bce < 16 -> q < 2^18

__device__ __forceinline__ int bin_of(float xv, float tv, float scale,
                                      int nbin_m1) {
  float g = fabsf(xv - tv);
  int b = (int)(g * scale);  // g >= 0 -> trunc == floor
  return b > nbin_m1 ? nbin_m1 : b;
}

// K1: per-block coarse bucket histogram (LDS), one row per block.
__global__ __launch_bounds__(SC_THREADS) void k1_count(
    const float4* __restrict__ x, const float4* __restrict__ t,
    unsigned* __restrict__ hists /*[SC_BLOCKS][NB_PAD]*/, int per_block_f4,
    float scale, int nbin_m1) {
  __shared__ unsigned cnt[NB_PAD];
  for (int i = threadIdx.x; i < NB_PAD; i += SC_THREADS) cnt[i] = 0;
  __syncthreads();
  int base = blockIdx.x * per_block_f4;
  for (int i = threadIdx.x; i < per_block_f4; i += SC_THREADS) {
    float4 xv = x[base + i];
    float4 tv = t[base + i];
    atomicAdd(&cnt[bin_of(xv.x, tv.x, scale, nbin_m1) >> BPB_SHIFT], 1u);
    atomicAdd(&cnt[bin_of(xv.y, tv.y, scale, nbin_m1) >> BPB_SHIFT], 1u);
    atomicAdd(&cnt[bin_of(xv.z, tv.z, scale, nbin_m1) >> BPB_SHIFT], 1u);
    atomicAdd(&cnt[bin_of(xv.w, tv.w, scale, nbin_m1) >> BPB_SHIFT], 1u);
  }
  __syncthreads();
  unsigned* row = hists + (size_t)blockIdx.x * NB_PAD;
  for (int i = threadIdx.x; i < NB_PAD; i += SC_THREADS) row[i] = cnt[i];
}

// K2a: per-bucket exclusive scan over the SC_BLOCKS block-rows.
// grid = nb, block = SC_BLOCKS threads.
__global__ __launch_bounds__(SC_BLOCKS) void k2a_colscan(
    const unsigned* __restrict__ hists, unsigned* __restrict__ rel,
    unsigned* __restrict__ colsum) {
  __shared__ unsigned v[SC_BLOCKS];
  int b = blockIdx.x;
  int g = threadIdx.x;
  unsigned val = hists[(size_t)g * NB_PAD + b];
  v[g] = val;
  __syncthreads();
  for (int off = 1; off < SC_BLOCKS; off <<= 1) {
    unsigned a = (g >= off) ? v[g - off] : 0u;
    __syncthreads();
    v[g] += a;
    __syncthreads();
  }
  rel[(size_t)g * NB_PAD + b] = v[g] - val;  // exclusive prefix
  if (g == SC_BLOCKS - 1) colsum[b] = v[g];  // bucket total
}

// K2b: exclusive scan of bucket totals -> bucket starts. 1 block.
__global__ __launch_bounds__(NB_PAD) void k2b_scan(
    const unsigned* __restrict__ colsum, unsigned* __restrict__ start,
    int nb) {
  __shared__ unsigned v[NB_PAD];
  int i = threadIdx.x;
  unsigned val = (i < nb) ? colsum[i] : 0u;
  v[i] = val;
  __syncthreads();
  for (int off = 1; off < NB_PAD; off <<= 1) {
    unsigned a = (i >= off) ? v[i - off] : 0u;
    __syncthreads();
    v[i] += a;
    __syncthreads();
  }
  if (i < nb) start[i] = v[i] - val;
}

// K3: scatter packed (bin_low<<18 | bce_q18) keys to exact per-(block,bucket)
// regions. No global atomics; ranks via LDS cursors.
__global__ __launch_bounds__(SC_THREADS) void k3_scatter(
    const float4* __restrict__ x, const float4* __restrict__ t,
    const unsigned* __restrict__ rel, const unsigned* __restrict__ start,
    unsigned* __restrict__ keys, int per_block_f4, float scale, int nbin_m1,
    int nb) {
  __shared__ unsigned cur[NB_PAD];
  const unsigned* relrow = rel + (size_t)blockIdx.x * NB_PAD;
  for (int i = threadIdx.x; i < nb; i += SC_THREADS)
    cur[i] = start[i] + relrow[i];
  __syncthreads();
  int base = blockIdx.x * per_block_f4;
  for (int i = threadIdx.x; i < per_block_f4; i += SC_THREADS) {
    float4 xv = x[base + i];
    float4 tv = t[base + i];
    float xs[4] = {xv.x, xv.y, xv.z, xv.w};
    float ts[4] = {tv.x, tv.y, tv.z, tv.w};
#pragma unroll
    for (int k = 0; k < 4; ++k) {
      int b = bin_of(xs[k], ts[k], scale, nbin_m1);
      float bce =
          -(ts[k] * logf(xs[k]) + (1.0f - ts[k]) * logf(1.0f - xs[k]));
      unsigned q = (unsigned)(bce * QSCALE + 0.5f);
      if (q > QMASK) q = QMASK;
      unsigned key = ((unsigned)(b & (BPB - 1)) << QBITS) | q;
      unsigned r = atomicAdd(&cur[b >> BPB_SHIFT], 1u);
      keys[r] = key;
    }
  }
}

// K4: one block per bucket. Packed LDS histogram: u32 = count<<24 | sum_q24.
// Integer accumulation -> order-independent -> deterministic.
__global__ __launch_bounds__(1024) void k4_bucket(
    const unsigned* __restrict__ keys, const unsigned* __restrict__ start,
    const unsigned* __restrict__ colsum, double* __restrict__ S_part,
    unsigned* __restrict__ nz) {
  __shared__ unsigned ph[BPB];  // 64 KB
  for (int i = threadIdx.x; i < BPB; i += 1024) ph[i] = 0u;
  __syncthreads();
  int b = blockIdx.x;
  unsigned s0 = start[b], c = colsum[b];
  for (unsigned i = threadIdx.x; i < c; i += 1024) {
    unsigned k = keys[s0 + i];
    atomicAdd(&ph[k >> QBITS], (1u << 24) | (k & QMASK));
  }
  __syncthreads();
  double S = 0.0;
  unsigned z = 0;
  for (int i = threadIdx.x; i < BPB; i += 1024) {
    unsigned p = ph[i];
    unsigned cc = p >> 24;
    if (cc) {
      z++;
      S += (double)((float)(p & 0xFFFFFFu) * (1.0f / QSCALE) / (float)cc);
    }
  }
  __syncthreads();  // all reads of ph done; reuse it for reduction
#pragma unroll
  for (int off = 32; off > 0; off >>= 1) {
    S += __shfl_down(S, off, 64);
    z += __shfl_down(z, off, 64);
  }
  double* dred = (double*)ph;     // ph[0..31]  -> 16 doubles
  unsigned* ired = ph + 32;       // ph[32..47] -> 16 uints
  int wid = threadIdx.x >> 6;
  if ((threadIdx.x & 63) == 0) {
    dred[wid] = S;
    ired[wid] = z;
  }
  __syncthreads();
  if (threadIdx.x == 0) {
    double st = 0.0;
    unsigned zt = 0;
    for (int w = 0; w < 16; ++w) {
      st += dred[w];
      zt += ired[w];
    }
    S_part[b] = st;
    atomicAdd(nz, zt);
  }
}

// K5: out = (sum_b S_b) / nz.
__global__ __launch_bounds__(256) void k5_final(
    const double* __restrict__ S_part, const unsigned* __restrict__ nz,
    float* __restrict__ out, int nb) {
  __shared__ double red[256];
  double s = 0.0;
  for (int i = threadIdx.x; i < nb; i += 256) s += S_part[i];
  red[threadIdx.x] = s;
  __syncthreads();
  for (int off = 128; off > 0; off >>= 1) {
    if (threadIdx.x < off) red[threadIdx.x] += red[threadIdx.x + off];
    __syncthreads();
  }
  if (threadIdx.x == 0) out[0] = (float)(red[0] / (double)(*nz));
}

// ---------------- fallback path (proven round-1 kernels) ----------------
#define FB_BLOCK 256
#define FB_GRID 2048

__global__ __launch_bounds__(FB_BLOCK) void ghm_hist_kernel(
    const float4* __restrict__ x, const float4* __restrict__ t,
    int* __restrict__ hist, int n4, float scale, int nbin_m1) {
  int i = blockIdx.x * blockDim.x + threadIdx.x;
  int stride = gridDim.x * blockDim.x;
  for (; i < n4; i += stride) {
    float4 xv = x[i];
    float4 tv = t[i];
    float gx[4] = {fabsf(xv.x - tv.x), fabsf(xv.y - tv.y),
                   fabsf(xv.z - tv.z), fabsf(xv.w - tv.w)};
#pragma unroll
    for (int k = 0; k < 4; ++k) {
      int b = (int)(gx[k] * scale);
      if (b > nbin_m1) b = nbin_m1;
      atomicAdd(&hist[b], 1);
    }
  }
}

__global__ __launch_bounds__(FB_BLOCK) void ghm_nz_kernel(
    const int* __restrict__ hist, int nbin, int* __restrict__ nz) {
  int i = blockIdx.x * blockDim.x + threadIdx.x;
  int stride = gridDim.x * blockDim.x;
  int c = 0;
  for (; i < nbin; i += stride) c += (hist[i] > 0) ? 1 : 0;
#pragma unroll
  for (int off = 32; off > 0; off >>= 1) c += __shfl_down(c, off, 64);
  if ((threadIdx.x & 63) == 0) atomicAdd(nz, c);
}

__global__ __launch_bounds__(FB_BLOCK) void ghm_loss_kernel(
    const float4* __restrict__ x, const float4* __restrict__ t,
    const int* __restrict__ hist, const int* __restrict__ nz,
    double* __restrict__ partials, int n4, float scale, int nbin_m1,
    float fN) {
  float nzf = (float)(*nz);
  double acc = 0.0;
  int i = blockIdx.x * blockDim.x + threadIdx.x;
  int stride = gridDim.x * blockDim.x;
  for (; i < n4; i += stride) {
    float4 xv = x[i];
    float4 tv = t[i];
    float xs[4] = {xv.x, xv.y, xv.z, xv.w};
    float ts[4] = {tv.x, tv.y, tv.z, tv.w};
    float s = 0.0f;
#pragma unroll
    for (int k = 0; k < 4; ++k) {
      float g = fabsf(xs[k] - ts[k]);
      int b = (int)(g * scale);
      if (b > nbin_m1) b = nbin_m1;
      float cntv = (float)hist[b];
      float gd = fmaxf(cntv * nzf, 1.0f);
      float w = fN / gd;
      float bce = -(ts[k] * logf(xs[k]) + (1.0f - ts[k]) * logf(1.0f - xs[k]));
      s += bce * w;
    }
    acc += (double)s;
  }
  __shared__ double sm[FB_BLOCK];
  sm[threadIdx.x] = acc;
  __syncthreads();
  for (int off = FB_BLOCK / 2; off > 0; off >>= 1) {
    if (threadIdx.x < off) sm[threadIdx.x] += sm[threadIdx.x + off];
    __syncthreads();
  }
  if (threadIdx.x == 0) partials[blockIdx.x] = sm[0];
}

__global__ __launch_bounds__(FB_BLOCK) void ghm_final_kernel(
    const double* __restrict__ partials, float* __restrict__ out, int nparts,
    double invN) {
  __shared__ double sm[FB_BLOCK];
  double a = 0.0;
  for (int i = threadIdx.x; i < nparts; i += FB_BLOCK) a += partials[i];
  sm[threadIdx.x] = a;
  __syncthreads();
  for (int off = FB_BLOCK / 2; off > 0; off >>= 1) {
    if (threadIdx.x < off) sm[threadIdx.x] += sm[threadIdx.x + off];
    __syncthreads();
  }
  if (threadIdx.x == 0) out[0] = (float)(sm[0] * invN);
}

extern "C" void kernel_launch(void* const* d_in, const int* in_sizes, int n_in,
                              void* d_out, int out_size, void* d_ws,
                              size_t ws_size, hipStream_t stream) {
  const float* x = (const float*)d_in[0];
  const float* t = (const float*)d_in[1];
  float* out = (float*)d_out;

  long long N = (long long)in_sizes[0];          // 33554432
  int nbin = (int)(N / 10);                      // 3355443
  float scale = (float)((double)nbin - 0.0001);  // == f32(nbin) here
  int n4 = (int)(N / 4);
  int nb = (nbin + BPB - 1) / BPB;  // 205 buckets

  // fast-path workspace layout
  size_t off_hists = 0;
  size_t off_rel = off_hists + (size_t)SC_BLOCKS * NB_PAD * 4;
  size_t off_start = off_rel + (size_t)SC_BLOCKS * NB_PAD * 4;
  size_t off_colsum = off_start + NB_PAD * 4;
  size_t off_nz = off_colsum + NB_PAD * 4;
  size_t off_Spart = off_nz + 256;
  size_t off_keys = (off_Spart + NB_PAD * 8 + 255) & ~(size_t)255;
  size_t needed = off_keys + (size_t)N * 4;

  bool fast = (ws_size >= needed) && (N % 4 == 0) &&
              (n4 % SC_BLOCKS == 0) && (nb <= NB_PAD);

  if (fast) {
    unsigned* hists = (unsigned*)((char*)d_ws + off_hists);
    unsigned* rel = (unsigned*)((char*)d_ws + off_rel);
    unsigned* start = (unsigned*)((char*)d_ws + off_start);
    unsigned* colsum = (unsigned*)((char*)d_ws + off_colsum);
    unsigned* nz = (unsigned*)((char*)d_ws + off_nz);
    double* S_part = (double*)((char*)d_ws + off_Spart);
    unsigned* keys = (unsigned*)((char*)d_ws + off_keys);
    int per_block_f4 = n4 / SC_BLOCKS;

    hipMemsetAsync(nz, 0, 4, stream);
    k1_count<<<SC_BLOCKS, SC_THREADS, 0, stream>>>(
        (const float4*)x, (const float4*)t, hists, per_block_f4, scale,
        nbin - 1);
    k2a_colscan<<<nb, SC_BLOCKS, 0, stream>>>(hists, rel, colsum);
    k2b_scan<<<1, NB_PAD, 0, stream>>>(colsum, start, nb);
    k3_scatter<<<SC_BLOCKS, SC_THREADS, 0, stream>>>(
        (const float4*)x, (const float4*)t, rel, start, keys, per_block_f4,
        scale, nbin - 1, nb);
    k4_bucket<<<nb, 1024, 0, stream>>>(keys, start, colsum, S_part, nz);
    k5_final<<<1, 256, 0, stream>>>(S_part, nz, out, nb);
  } else {
    // round-1 proven path
    int* hist = (int*)d_ws;
    size_t hist_bytes = (size_t)nbin * 4;
    int* nzi = (int*)((char*)d_ws + hist_bytes);
    size_t part_off = (hist_bytes + 4 + 7) & ~(size_t)7;
    double* partials = (double*)((char*)d_ws + part_off);

    hipMemsetAsync(d_ws, 0, part_off, stream);
    ghm_hist_kernel<<<FB_GRID, FB_BLOCK, 0, stream>>>(
        (const float4*)x, (const float4*)t, hist, n4, scale, nbin - 1);
    ghm_nz_kernel<<<FB_GRID, FB_BLOCK, 0, stream>>>(hist, nbin, (int*)nzi);
    ghm_loss_kernel<<<FB_GRID, FB_BLOCK, 0, stream>>>(
        (const float4*)x, (const float4*)t, hist, (const int*)nzi, partials,
        n4, scale, nbin - 1, (float)N);
    ghm_final_kernel<<<1, FB_BLOCK, 0, stream>>>(partials, out, FB_GRID,
                                                 1.0 / (double)N);
  }
}

// Round 4
// 333.128 us; speedup vs baseline: 5.2471x; 1.3307x over previous
//
#include <hip/hip_runtime.h>
#include <math.h>

// ---------------- fast path geometry ----------------
#define SC_BLOCKS 512   // stripe blocks for K1/K3 (per-block bucket hists)
#define SC_THREADS 512
#define BPB 8192        // bins per bucket (power of two)
#define BPB_SHIFT 13
#define NB_PAD 512      // padded bucket-array stride (>= nb = 410)
#define NB_MAX 420      // max buckets supported by K3 staging LDS
#define QBITS 18
#define QMASK ((1u << QBITS) - 1u)
#define QSCALE 16384.0f  // 2^14: q = bce * 2^14, bce < 16 -> q < 2^18
#define CAP 32           // staged keys per bucket per tile
#define TILE_F4 1024     // float4s per tile (= 4096 elements)
#define NTILE 16         // tiles per block: 16*1024 f4 = 65536 elements

__device__ __forceinline__ int bin_of(float xv, float tv, float scale,
                                      int nbin_m1) {
  float g = fabsf(xv - tv);
  int b = (int)(g * scale);  // g >= 0 -> trunc == floor
  return b > nbin_m1 ? nbin_m1 : b;
}

// K1: per-block coarse bucket histogram (LDS), one row per block.
__global__ __launch_bounds__(SC_THREADS) void k1_count(
    const float4* __restrict__ x, const float4* __restrict__ t,
    unsigned* __restrict__ hists /*[SC_BLOCKS][NB_PAD]*/, int per_block_f4,
    float scale, int nbin_m1) {
  __shared__ unsigned cnt[NB_PAD];
  for (int i = threadIdx.x; i < NB_PAD; i += SC_THREADS) cnt[i] = 0;
  __syncthreads();
  int base = blockIdx.x * per_block_f4;
  for (int i = threadIdx.x; i < per_block_f4; i += SC_THREADS) {
    float4 xv = x[base + i];
    float4 tv = t[base + i];
    atomicAdd(&cnt[bin_of(xv.x, tv.x, scale, nbin_m1) >> BPB_SHIFT], 1u);
    atomicAdd(&cnt[bin_of(xv.y, tv.y, scale, nbin_m1) >> BPB_SHIFT], 1u);
    atomicAdd(&cnt[bin_of(xv.z, tv.z, scale, nbin_m1) >> BPB_SHIFT], 1u);
    atomicAdd(&cnt[bin_of(xv.w, tv.w, scale, nbin_m1) >> BPB_SHIFT], 1u);
  }
  __syncthreads();
  unsigned* row = hists + (size_t)blockIdx.x * NB_PAD;
  for (int i = threadIdx.x; i < NB_PAD; i += SC_THREADS) row[i] = cnt[i];
}

// K2a: per-bucket exclusive scan over the SC_BLOCKS block-rows.
__global__ __launch_bounds__(SC_BLOCKS) void k2a_colscan(
    const unsigned* __restrict__ hists, unsigned* __restrict__ rel,
    unsigned* __restrict__ colsum) {
  __shared__ unsigned v[SC_BLOCKS];
  int b = blockIdx.x;
  int g = threadIdx.x;
  unsigned val = hists[(size_t)g * NB_PAD + b];
  v[g] = val;
  __syncthreads();
  for (int off = 1; off < SC_BLOCKS; off <<= 1) {
    unsigned a = (g >= off) ? v[g - off] : 0u;
    __syncthreads();
    v[g] += a;
    __syncthreads();
  }
  rel[(size_t)g * NB_PAD + b] = v[g] - val;  // exclusive prefix
  if (g == SC_BLOCKS - 1) colsum[b] = v[g];  // bucket total
}

// K2b: exclusive scan of bucket totals -> bucket starts. 1 block.
__global__ __launch_bounds__(NB_PAD) void k2b_scan(
    const unsigned* __restrict__ colsum, unsigned* __restrict__ start,
    int nb) {
  __shared__ unsigned v[NB_PAD];
  int i = threadIdx.x;
  unsigned val = (i < nb) ? colsum[i] : 0u;
  v[i] = val;
  __syncthreads();
  for (int off = 1; off < NB_PAD; off <<= 1) {
    unsigned a = (i >= off) ? v[i - off] : 0u;
    __syncthreads();
    v[i] += a;
    __syncthreads();
  }
  if (i < nb) start[i] = v[i] - val;
}

// K3: tiled staged scatter. Per tile: keys -> per-bucket LDS staging
// (overflow -> direct global store at exact rank, still correct), then
// wave-coalesced flush. Rank order is atomic-order-dependent but K4's
// aggregation is order-free, so the final output is deterministic.
__global__ __launch_bounds__(SC_THREADS) void k3_scatter(
    const float4* __restrict__ x, const float4* __restrict__ t,
    const unsigned* __restrict__ rel, const unsigned* __restrict__ start,
    unsigned* __restrict__ keys, float scale, int nbin_m1, int nb) {
  __shared__ unsigned gbase[NB_MAX];        // 1.68 KB
  __shared__ unsigned tcnt[NB_MAX];         // 1.68 KB
  __shared__ unsigned stage[NB_MAX * CAP];  // 53.8 KB  (total ~57.1 KB)
  const unsigned* relrow = rel + (size_t)blockIdx.x * NB_PAD;
  for (int i = threadIdx.x; i < nb; i += SC_THREADS)
    gbase[i] = start[i] + relrow[i];
  int base = blockIdx.x * (TILE_F4 * NTILE);
  int wid = threadIdx.x >> 6;
  int lane = threadIdx.x & 63;
  for (int tile = 0; tile < NTILE; ++tile) {
    for (int i = threadIdx.x; i < nb; i += SC_THREADS) tcnt[i] = 0;
    __syncthreads();
#pragma unroll
    for (int j = 0; j < 2; ++j) {
      int f4i = base + tile * TILE_F4 + j * SC_THREADS + threadIdx.x;
      float4 xv = x[f4i];
      float4 tv = t[f4i];
      float xs[4] = {xv.x, xv.y, xv.z, xv.w};
      float ts[4] = {tv.x, tv.y, tv.z, tv.w};
#pragma unroll
      for (int k = 0; k < 4; ++k) {
        int b = bin_of(xs[k], ts[k], scale, nbin_m1);
        float bce =
            -(ts[k] * logf(xs[k]) + (1.0f - ts[k]) * logf(1.0f - xs[k]));
        unsigned q = (unsigned)(bce * QSCALE + 0.5f);
        if (q > QMASK) q = QMASK;
        unsigned key = ((unsigned)(b & (BPB - 1)) << QBITS) | q;
        int bkt = b >> BPB_SHIFT;
        unsigned r = atomicAdd(&tcnt[bkt], 1u);
        if (r < CAP)
          stage[bkt * CAP + r] = key;
        else
          keys[gbase[bkt] + r] = key;  // rare overflow: exact rank
      }
    }
    __syncthreads();
    // flush: wave w handles buckets w, w+8, ... with lane-coalesced stores
    for (int bkt = wid; bkt < nb; bkt += (SC_THREADS / 64)) {
      unsigned cf = tcnt[bkt];
      unsigned c = cf < CAP ? cf : CAP;
      unsigned g = gbase[bkt];
      for (unsigned i = lane; i < c; i += 64)
        keys[g + i] = stage[bkt * CAP + i];
      if (lane == 0) gbase[bkt] = g + cf;
    }
    __syncthreads();
  }
}

// K4: one block per bucket. Packed LDS histogram: u32 = count<<24 | sum_q24.
// Integer accumulation -> order-independent -> deterministic.
__global__ __launch_bounds__(1024) void k4_bucket(
    const unsigned* __restrict__ keys, const unsigned* __restrict__ start,
    const unsigned* __restrict__ colsum, double* __restrict__ S_part,
    unsigned* __restrict__ nz) {
  __shared__ unsigned ph[BPB];  // 32 KB
  for (int i = threadIdx.x; i < BPB; i += 1024) ph[i] = 0u;
  __syncthreads();
  int b = blockIdx.x;
  unsigned s0 = start[b], c = colsum[b];
  for (unsigned i = threadIdx.x; i < c; i += 1024) {
    unsigned k = keys[s0 + i];
    atomicAdd(&ph[k >> QBITS], (1u << 24) | (k & QMASK));
  }
  __syncthreads();
  double S = 0.0;
  unsigned z = 0;
  for (int i = threadIdx.x; i < BPB; i += 1024) {
    unsigned p = ph[i];
    unsigned cc = p >> 24;
    if (cc) {
      z++;
      S += (double)((float)(p & 0xFFFFFFu) * (1.0f / QSCALE) / (float)cc);
    }
  }
  __syncthreads();  // all reads of ph done; reuse it for reduction
#pragma unroll
  for (int off = 32; off > 0; off >>= 1) {
    S += __shfl_down(S, off, 64);
    z += __shfl_down(z, off, 64);
  }
  double* dred = (double*)ph;  // ph[0..31]  -> 16 doubles
  unsigned* ired = ph + 32;    // ph[32..47] -> 16 uints
  int wid = threadIdx.x >> 6;
  if ((threadIdx.x & 63) == 0) {
    dred[wid] = S;
    ired[wid] = z;
  }
  __syncthreads();
  if (threadIdx.x == 0) {
    double st = 0.0;
    unsigned zt = 0;
    for (int w = 0; w < 16; ++w) {
      st += dred[w];
      zt += ired[w];
    }
    S_part[b] = st;
    atomicAdd(nz, zt);
  }
}

// K5: out = (sum_b S_b) / nz.
__global__ __launch_bounds__(256) void k5_final(
    const double* __restrict__ S_part, const unsigned* __restrict__ nz,
    float* __restrict__ out, int nb) {
  __shared__ double red[256];
  double s = 0.0;
  for (int i = threadIdx.x; i < nb; i += 256) s += S_part[i];
  red[threadIdx.x] = s;
  __syncthreads();
  for (int off = 128; off > 0; off >>= 1) {
    if (threadIdx.x < off) red[threadIdx.x] += red[threadIdx.x + off];
    __syncthreads();
  }
  if (threadIdx.x == 0) out[0] = (float)(red[0] / (double)(*nz));
}

// ---------------- fallback path (proven round-1 kernels) ----------------
#define FB_BLOCK 256
#define FB_GRID 2048

__global__ __launch_bounds__(FB_BLOCK) void ghm_hist_kernel(
    const float4* __restrict__ x, const float4* __restrict__ t,
    int* __restrict__ hist, int n4, float scale, int nbin_m1) {
  int i = blockIdx.x * blockDim.x + threadIdx.x;
  int stride = gridDim.x * blockDim.x;
  for (; i < n4; i += stride) {
    float4 xv = x[i];
    float4 tv = t[i];
    float gx[4] = {fabsf(xv.x - tv.x), fabsf(xv.y - tv.y),
                   fabsf(xv.z - tv.z), fabsf(xv.w - tv.w)};
#pragma unroll
    for (int k = 0; k < 4; ++k) {
      int b = (int)(gx[k] * scale);
      if (b > nbin_m1) b = nbin_m1;
      atomicAdd(&hist[b], 1);
    }
  }
}

__global__ __launch_bounds__(FB_BLOCK) void ghm_nz_kernel(
    const int* __restrict__ hist, int nbin, int* __restrict__ nz) {
  int i = blockIdx.x * blockDim.x + threadIdx.x;
  int stride = gridDim.x * blockDim.x;
  int c = 0;
  for (; i < nbin; i += stride) c += (hist[i] > 0) ? 1 : 0;
#pragma unroll
  for (int off = 32; off > 0; off >>= 1) c += __shfl_down(c, off, 64);
  if ((threadIdx.x & 63) == 0) atomicAdd(nz, c);
}

__global__ __launch_bounds__(FB_BLOCK) void ghm_loss_kernel(
    const float4* __restrict__ x, const float4* __restrict__ t,
    const int* __restrict__ hist, const int* __restrict__ nz,
    double* __restrict__ partials, int n4, float scale, int nbin_m1,
    float fN) {
  float nzf = (float)(*nz);
  double acc = 0.0;
  int i = blockIdx.x * blockDim.x + threadIdx.x;
  int stride = gridDim.x * blockDim.x;
  for (; i < n4; i += stride) {
    float4 xv = x[i];
    float4 tv = t[i];
    float xs[4] = {xv.x, xv.y, xv.z, xv.w};
    float ts[4] = {tv.x, tv.y, tv.z, tv.w};
    float s = 0.0f;
#pragma unroll
    for (int k = 0; k < 4; ++k) {
      float g = fabsf(xs[k] - ts[k]);
      int b = (int)(g * scale);
      if (b > nbin_m1) b = nbin_m1;
      float cntv = (float)hist[b];
      float gd = fmaxf(cntv * nzf, 1.0f);
      float w = fN / gd;
      float bce = -(ts[k] * logf(xs[k]) + (1.0f - ts[k]) * logf(1.0f - xs[k]));
      s += bce * w;
    }
    acc += (double)s;
  }
  __shared__ double sm[FB_BLOCK];
  sm[threadIdx.x] = acc;
  __syncthreads();
  for (int off = FB_BLOCK / 2; off > 0; off >>= 1) {
    if (threadIdx.x < off) sm[threadIdx.x] += sm[threadIdx.x + off];
    __syncthreads();
  }
  if (threadIdx.x == 0) partials[blockIdx.x] = sm[0];
}

__global__ __launch_bounds__(FB_BLOCK) void ghm_final_kernel(
    const double* __restrict__ partials, float* __restrict__ out, int nparts,
    double invN) {
  __shared__ double sm[FB_BLOCK];
  double a = 0.0;
  for (int i = threadIdx.x; i < nparts; i += FB_BLOCK) a += partials[i];
  sm[threadIdx.x] = a;
  __syncthreads();
  for (int off = FB_BLOCK / 2; off > 0; off >>= 1) {
    if (threadIdx.x < off) sm[threadIdx.x] += sm[threadIdx.x + off];
    __syncthreads();
  }
  if (threadIdx.x == 0) out[0] = (float)(sm[0] * invN);
}

extern "C" void kernel_launch(void* const* d_in, const int* in_sizes, int n_in,
                              void* d_out, int out_size, void* d_ws,
                              size_t ws_size, hipStream_t stream) {
  const float* x = (const float*)d_in[0];
  const float* t = (const float*)d_in[1];
  float* out = (float*)d_out;

  long long N = (long long)in_sizes[0];          // 33554432
  int nbin = (int)(N / 10);                      // 3355443
  float scale = (float)((double)nbin - 0.0001);  // == f32(nbin) here
  int n4 = (int)(N / 4);
  int nb = (nbin + BPB - 1) / BPB;  // 410 buckets

  // fast-path workspace layout
  size_t off_hists = 0;
  size_t off_rel = off_hists + (size_t)SC_BLOCKS * NB_PAD * 4;
  size_t off_start = off_rel + (size_t)SC_BLOCKS * NB_PAD * 4;
  size_t off_colsum = off_start + NB_PAD * 4;
  size_t off_nz = off_colsum + NB_PAD * 4;
  size_t off_Spart = off_nz + 256;
  size_t off_keys = (off_Spart + NB_PAD * 8 + 255) & ~(size_t)255;
  size_t needed = off_keys + (size_t)N * 4;

  bool fast = (ws_size >= needed) && (N % 4 == 0) &&
              (n4 == SC_BLOCKS * TILE_F4 * NTILE) && (nb <= NB_MAX);

  if (fast) {
    unsigned* hists = (unsigned*)((char*)d_ws + off_hists);
    unsigned* rel = (unsigned*)((char*)d_ws + off_rel);
    unsigned* start = (unsigned*)((char*)d_ws + off_start);
    unsigned* colsum = (unsigned*)((char*)d_ws + off_colsum);
    unsigned* nz = (unsigned*)((char*)d_ws + off_nz);
    double* S_part = (double*)((char*)d_ws + off_Spart);
    unsigned* keys = (unsigned*)((char*)d_ws + off_keys);
    int per_block_f4 = n4 / SC_BLOCKS;  // 16384

    hipMemsetAsync(nz, 0, 4, stream);
    k1_count<<<SC_BLOCKS, SC_THREADS, 0, stream>>>(
        (const float4*)x, (const float4*)t, hists, per_block_f4, scale,
        nbin - 1);
    k2a_colscan<<<nb, SC_BLOCKS, 0, stream>>>(hists, rel, colsum);
    k2b_scan<<<1, NB_PAD, 0, stream>>>(colsum, start, nb);
    k3_scatter<<<SC_BLOCKS, SC_THREADS, 0, stream>>>(
        (const float4*)x, (const float4*)t, rel, start, keys, scale, nbin - 1,
        nb);
    k4_bucket<<<nb, 1024, 0, stream>>>(keys, start, colsum, S_part, nz);
    k5_final<<<1, 256, 0, stream>>>(S_part, nz, out, nb);
  } else {
    // round-1 proven path
    int* hist = (int*)d_ws;
    size_t hist_bytes = (size_t)nbin * 4;
    int* nzi = (int*)((char*)d_ws + hist_bytes);
    size_t part_off = (hist_bytes + 4 + 7) & ~(size_t)7;
    double* partials = (double*)((char*)d_ws + part_off);

    hipMemsetAsync(d_ws, 0, part_off, stream);
    ghm_hist_kernel<<<FB_GRID, FB_BLOCK, 0, stream>>>(
        (const float4*)x, (const float4*)t, hist, n4, scale, nbin - 1);
    ghm_nz_kernel<<<FB_GRID, FB_BLOCK, 0, stream>>>(hist, nbin, (int*)nzi);
    ghm_loss_kernel<<<FB_GRID, FB_BLOCK, 0, stream>>>(
        (const float4*)x, (const float4*)t, hist, (const int*)nzi, partials,
        n4, scale, nbin - 1, (float)N);
    ghm_final_kernel<<<1, FB_BLOCK, 0, stream>>>(partials, out, FB_GRID,
                                                 1.0 / (double)N);
  }
}